// Round 4
// baseline (836.735 us; speedup 1.0000x reference)
//
#include <hip/hip_runtime.h>

typedef unsigned short u16;
typedef unsigned int u32;

#define C_DIM 192
#define N_TOK 16384
#define TILE_N 16
#define M_LEN 256
#define HD 32
#define NH 6

__device__ __forceinline__ float bf2f(u32 u) {
    union { u32 i; float f; } v; v.i = (u & 0xffffu) << 16; return v.f;
}
__device__ __forceinline__ u16 f2bf(float f) {
    union { float f; u32 i; } v; v.f = f;
    u32 x = v.i;
    return (u16)((x + 0x7fffu + ((x >> 16) & 1u)) >> 16);
}
__device__ __forceinline__ void unpack8(uint4 u, float* f) {
    f[0] = bf2f(u.x); f[1] = bf2f(u.x >> 16);
    f[2] = bf2f(u.y); f[3] = bf2f(u.y >> 16);
    f[4] = bf2f(u.z); f[5] = bf2f(u.z >> 16);
    f[6] = bf2f(u.w); f[7] = bf2f(u.w >> 16);
}

// ---------------- Kernel A: LN1 + Q projection (q bf16 -> d_out lo half) ----
// grid: 4*1024 blocks, 192 threads
__global__ __launch_bounds__(192) void ln1_q_kernel(
    const float* __restrict__ x, const float* __restrict__ g,
    const float* __restrict__ beta, const float* __restrict__ Wq,
    u16* __restrict__ q)
{
    __shared__ float xs[C_DIM * TILE_N];   // [c][nn]
    __shared__ float mu_s[TILE_N], rs_s[TILE_N];
    __shared__ float gl[C_DIM], bl[C_DIM];
    int b = blockIdx.x >> 10;
    int n0 = (blockIdx.x & 1023) * TILE_N;
    int tid = threadIdx.x;
    gl[tid] = g[tid]; bl[tid] = beta[tid];
    for (int i = tid; i < C_DIM * TILE_N; i += 192) {
        int c = i >> 4, nn = i & 15;
        xs[i] = x[((size_t)(b * C_DIM + c) << 14) + n0 + nn];
    }
    __syncthreads();
    if (tid < TILE_N) {
        float s = 0.f, s2 = 0.f;
        for (int c = 0; c < C_DIM; ++c) {
            float v = xs[c * TILE_N + tid]; s += v; s2 += v * v;
        }
        float mu = s * (1.f / C_DIM);
        float var = s2 * (1.f / C_DIM) - mu * mu;
        mu_s[tid] = mu; rs_s[tid] = rsqrtf(var + 1e-5f);
    }
    __syncthreads();
    for (int i = tid; i < C_DIM * TILE_N; i += 192) {
        int c = i >> 4, nn = i & 15;
        xs[i] = (xs[i] - mu_s[nn]) * rs_s[nn] * gl[c] + bl[c];
    }
    __syncthreads();
    int j = tid;
    float acc[TILE_N];
#pragma unroll
    for (int nn = 0; nn < TILE_N; ++nn) acc[nn] = 0.f;
    for (int c = 0; c < C_DIM; ++c) {
        float w = Wq[c * C_DIM + j];
        const float* row = &xs[c * TILE_N];
#pragma unroll
        for (int nn = 0; nn < TILE_N; ++nn) acc[nn] += row[nn] * w;
    }
    u16* qp = q + (size_t)(b * N_TOK + n0) * C_DIM + j;
#pragma unroll
    for (int nn = 0; nn < TILE_N; ++nn) qp[nn * C_DIM] = f2bf(acc[nn]);
}

// ---------------- Kernel C: fused LN2 + KV-proj + attention ----------------
// grid: B*NH*(N/1024) = 384 blocks, 256 threads
__global__ __launch_bounds__(256) void attn_kernel(
    const u16* __restrict__ q, const float* __restrict__ prior,
    const float* __restrict__ g2, const float* __restrict__ b2,
    const float* __restrict__ Wkv, u16* __restrict__ att)
{
    __shared__ float Kt[M_LEN * HD];
    __shared__ float Vt[M_LEN * HD];
    int t  = blockIdx.x & 15;
    int bh = blockIdx.x >> 4;
    int h = bh % NH;
    int b = bh / NH;
    int tid = threadIdx.x;

    // ---- phase 1: LN2 + KV projection, row m = tid ----
    {
        int m = tid;
        const float4* pv = (const float4*)(prior + (size_t)(b * M_LEN + m) * C_DIM);
        float s = 0.f, s2 = 0.f;
        for (int i = 0; i < 48; ++i) {
            float4 f = pv[i];
            s += f.x + f.y + f.z + f.w;
            s2 += f.x * f.x + f.y * f.y + f.z * f.z + f.w * f.w;
        }
        float mu = s * (1.f / C_DIM);
        float rs = rsqrtf(s2 * (1.f / C_DIM) - mu * mu + 1e-5f);
        float ka[HD], va[HD];
#pragma unroll
        for (int d = 0; d < HD; ++d) { ka[d] = 0.f; va[d] = 0.f; }
        const float* wbase = Wkv + h * HD;          // K cols for this head
        for (int i = 0; i < 48; ++i) {
            float4 f = pv[i];
            float fv[4] = { f.x, f.y, f.z, f.w };
#pragma unroll
            for (int j = 0; j < 4; ++j) {
                int c = i * 4 + j;
                float pn = (fv[j] - mu) * rs * g2[c] + b2[c];
                const float* wk = wbase + c * 384;  // uniform addr -> scalar loads
                const float* wv = wk + 192;
#pragma unroll
                for (int d = 0; d < HD; ++d) {
                    ka[d] += pn * wk[d];
                    va[d] += pn * wv[d];
                }
            }
        }
#pragma unroll
        for (int d = 0; d < HD; ++d) { Kt[m * HD + d] = ka[d]; Vt[m * HD + d] = va[d]; }
    }
    __syncthreads();

    // ---- phase 2: attention for 1024 tokens (4 reps) ----
    const float scale = 0.17677669529663687f;   // 1/sqrt(32)
    for (int rep = 0; rep < 4; ++rep) {
        int n = t * 1024 + rep * 256 + tid;
        const uint4* qv = (const uint4*)(q + (size_t)(b * N_TOK + n) * C_DIM + h * HD);
        float qr[HD];
        unpack8(qv[0], qr); unpack8(qv[1], qr + 8);
        unpack8(qv[2], qr + 16); unpack8(qv[3], qr + 24);
        float mx = -1e30f, l = 0.f;
        float o[HD];
#pragma unroll
        for (int d = 0; d < HD; ++d) o[d] = 0.f;
        for (int m = 0; m < M_LEN; ++m) {
            const float4* kr = (const float4*)&Kt[m * HD];
            float sdot = 0.f;
#pragma unroll
            for (int d4 = 0; d4 < 8; ++d4) {
                float4 kk = kr[d4];
                sdot += qr[4 * d4] * kk.x + qr[4 * d4 + 1] * kk.y
                      + qr[4 * d4 + 2] * kk.z + qr[4 * d4 + 3] * kk.w;
            }
            sdot *= scale;
            const float4* vr = (const float4*)&Vt[m * HD];
            if (sdot <= mx) {
                float p = __expf(sdot - mx);
                l += p;
#pragma unroll
                for (int d4 = 0; d4 < 8; ++d4) {
                    float4 vv = vr[d4];
                    o[4 * d4]     += p * vv.x;
                    o[4 * d4 + 1] += p * vv.y;
                    o[4 * d4 + 2] += p * vv.z;
                    o[4 * d4 + 3] += p * vv.w;
                }
            } else {
                float r = __expf(mx - sdot);
                l = l * r + 1.f;
#pragma unroll
                for (int d4 = 0; d4 < 8; ++d4) {
                    float4 vv = vr[d4];
                    o[4 * d4]     = o[4 * d4] * r     + vv.x;
                    o[4 * d4 + 1] = o[4 * d4 + 1] * r + vv.y;
                    o[4 * d4 + 2] = o[4 * d4 + 2] * r + vv.z;
                    o[4 * d4 + 3] = o[4 * d4 + 3] * r + vv.w;
                }
                mx = sdot;
            }
        }
        float inv = 1.f / l;
        uint4* ov = (uint4*)(att + (size_t)(b * N_TOK + n) * C_DIM + h * HD);
#pragma unroll
        for (int i2 = 0; i2 < 4; ++i2) {
            uint4 w;
            w.x = (u32)f2bf(o[8 * i2 + 0] * inv) | ((u32)f2bf(o[8 * i2 + 1] * inv) << 16);
            w.y = (u32)f2bf(o[8 * i2 + 2] * inv) | ((u32)f2bf(o[8 * i2 + 3] * inv) << 16);
            w.z = (u32)f2bf(o[8 * i2 + 4] * inv) | ((u32)f2bf(o[8 * i2 + 5] * inv) << 16);
            w.w = (u32)f2bf(o[8 * i2 + 6] * inv) | ((u32)f2bf(o[8 * i2 + 7] * inv) << 16);
            ov[i2] = w;
        }
    }
}

// ---------------- Kernel D: out projection + bias + residual (y fp32) -------
// grid: 4096 blocks, 192 threads
__global__ __launch_bounds__(192) void proj_res_kernel(
    const u16* __restrict__ att, const float* __restrict__ Wp,
    const float* __restrict__ bp, const float* __restrict__ x,
    float* __restrict__ y)
{
    __shared__ float fs[C_DIM * (TILE_N + 1)];   // [j][nn], stride 17
    int b = blockIdx.x >> 10;
    int n0 = (blockIdx.x & 1023) * TILE_N;
    int tid = threadIdx.x;   // j = tid
#pragma unroll
    for (int nn = 0; nn < TILE_N; ++nn) {
        fs[tid * (TILE_N + 1) + nn] =
            bf2f(att[(size_t)(b * N_TOK + n0 + nn) * C_DIM + tid]);
    }
    __syncthreads();
    int c = tid;
    float acc[TILE_N];
#pragma unroll
    for (int nn = 0; nn < TILE_N; ++nn) acc[nn] = 0.f;
    for (int j = 0; j < C_DIM; ++j) {
        float w = Wp[j * C_DIM + c];
        const float* row = &fs[j * (TILE_N + 1)];
#pragma unroll
        for (int nn = 0; nn < TILE_N; ++nn) acc[nn] += row[nn] * w;
    }
    float bias = bp[c];
    size_t base = ((size_t)(b * C_DIM + c) << 14) + n0;
    const float4* xv = (const float4*)(x + base);
    float4* yv = (float4*)(y + base);
#pragma unroll
    for (int i4 = 0; i4 < 4; ++i4) {
        float4 u = xv[i4];
        float4 w;
        w.x = acc[4 * i4 + 0] + bias + u.x;
        w.y = acc[4 * i4 + 1] + bias + u.y;
        w.z = acc[4 * i4 + 2] + bias + u.z;
        w.w = acc[4 * i4 + 3] + bias + u.w;
        yv[i4] = w;
    }
}

extern "C" void kernel_launch(void* const* d_in, const int* in_sizes, int n_in,
                              void* d_out, int out_size, void* d_ws, size_t ws_size,
                              hipStream_t stream) {
    const float* x     = (const float*)d_in[0];
    const float* prior = (const float*)d_in[1];
    const float* ln1_g = (const float*)d_in[2];
    const float* ln1_b = (const float*)d_in[3];
    const float* ln2_g = (const float*)d_in[4];
    const float* ln2_b = (const float*)d_in[5];
    const float* Wq    = (const float*)d_in[6];
    const float* Wkv   = (const float*)d_in[7];
    const float* Wp    = (const float*)d_in[8];
    const float* bp    = (const float*)d_in[9];

    // q (bf16, 25.2 MB) staged in the first half of d_out (fp32, 50.3 MB);
    // consumed by attn before proj_res overwrites d_out with y.
    // att (bf16, 25.2 MB) is the only d_ws tenant.
    u16*   q   = (u16*)d_out;
    u16*   att = (u16*)d_ws;
    float* y   = (float*)d_out;

    ln1_q_kernel<<<4096, 192, 0, stream>>>(x, ln1_g, ln1_b, Wq, q);
    attn_kernel<<<384, 256, 0, stream>>>(q, prior, ln2_g, ln2_b, Wkv, att);
    proj_res_kernel<<<4096, 192, 0, stream>>>(att, Wp, bp, x, y);
}

// Round 5
// 408.993 us; speedup vs baseline: 2.0458x; 2.0458x over previous
//
#include <hip/hip_runtime.h>

typedef unsigned short u16;
typedef unsigned int u32;

#define C_DIM 192
#define N_TOK 16384
#define TILE_N 16
#define M_LEN 256
#define HD 32
#define NH 6

typedef __attribute__((ext_vector_type(8))) short short8v;
typedef __attribute__((ext_vector_type(4))) float float4v;

__device__ __forceinline__ float bf2f(u32 u) {
    union { u32 i; float f; } v; v.i = (u & 0xffffu) << 16; return v.f;
}
__device__ __forceinline__ u16 f2bf(float f) {
    union { float f; u32 i; } v; v.f = f;
    u32 x = v.i;
    return (u16)((x + 0x7fffu + ((x >> 16) & 1u)) >> 16);
}

// ---------------- Kernel A: LN1 + Q projection (q bf16 -> d_out lo) ---------
__global__ __launch_bounds__(192) void ln1_q_kernel(
    const float* __restrict__ x, const float* __restrict__ g,
    const float* __restrict__ beta, const float* __restrict__ Wq,
    u16* __restrict__ q)
{
    __shared__ float xs[C_DIM * TILE_N];   // [c][nn]
    __shared__ float mu_s[TILE_N], rs_s[TILE_N];
    __shared__ float gl[C_DIM], bl[C_DIM];
    int b = blockIdx.x >> 10;
    int n0 = (blockIdx.x & 1023) * TILE_N;
    int tid = threadIdx.x;
    gl[tid] = g[tid]; bl[tid] = beta[tid];
    for (int i = tid; i < C_DIM * TILE_N; i += 192) {
        int c = i >> 4, nn = i & 15;
        xs[i] = x[((size_t)(b * C_DIM + c) << 14) + n0 + nn];
    }
    __syncthreads();
    if (tid < TILE_N) {
        float s = 0.f, s2 = 0.f;
        for (int c = 0; c < C_DIM; ++c) {
            float v = xs[c * TILE_N + tid]; s += v; s2 += v * v;
        }
        float mu = s * (1.f / C_DIM);
        float var = s2 * (1.f / C_DIM) - mu * mu;
        mu_s[tid] = mu; rs_s[tid] = rsqrtf(var + 1e-5f);
    }
    __syncthreads();
    for (int i = tid; i < C_DIM * TILE_N; i += 192) {
        int c = i >> 4, nn = i & 15;
        xs[i] = (xs[i] - mu_s[nn]) * rs_s[nn] * gl[c] + bl[c];
    }
    __syncthreads();
    int j = tid;
    float acc[TILE_N];
#pragma unroll
    for (int nn = 0; nn < TILE_N; ++nn) acc[nn] = 0.f;
    for (int c = 0; c < C_DIM; ++c) {
        float w = Wq[c * C_DIM + j];
        const float* row = &xs[c * TILE_N];
#pragma unroll
        for (int nn = 0; nn < TILE_N; ++nn) acc[nn] += row[nn] * w;
    }
    u16* qp = q + (size_t)(b * N_TOK + n0) * C_DIM + j;
#pragma unroll
    for (int nn = 0; nn < TILE_N; ++nn) qp[nn * C_DIM] = f2bf(acc[nn]);
}

// ---------------- Kernel B: LN2 + KV projection (fp32 k/v -> d_out hi) -----
// grid: B*M = 1024 blocks, 192 threads
__global__ __launch_bounds__(192) void ln2_kv_kernel(
    const float* __restrict__ prior, const float* __restrict__ g,
    const float* __restrict__ beta, const float* __restrict__ Wkv,
    float* __restrict__ k, float* __restrict__ v)
{
    __shared__ float pr[C_DIM];
    __shared__ float stats[2];
    int row = blockIdx.x;
    int tid = threadIdx.x;
    float val = prior[row * C_DIM + tid];
    pr[tid] = val;
    __syncthreads();
    if (tid == 0) {
        float s = 0.f, s2 = 0.f;
        for (int c = 0; c < C_DIM; ++c) { float t = pr[c]; s += t; s2 += t * t; }
        float mu = s * (1.f / C_DIM);
        stats[0] = mu;
        stats[1] = rsqrtf(s2 * (1.f / C_DIM) - mu * mu + 1e-5f);
    }
    __syncthreads();
    float xn = (val - stats[0]) * stats[1] * g[tid] + beta[tid];
    __syncthreads();
    pr[tid] = xn;
    __syncthreads();
    float ka = 0.f, va = 0.f;
    for (int c = 0; c < C_DIM; ++c) {
        float p = pr[c];
        ka += p * Wkv[c * 384 + tid];
        va += p * Wkv[c * 384 + 192 + tid];
    }
    k[row * C_DIM + tid] = ka;
    v[row * C_DIM + tid] = va;
}

// ---------------- Kernel C: MFMA attention ----------------
// grid: B*NH*256 = 6144 blocks, 256 threads (4 waves x 16 tokens = 64 tokens).
// S^T orientation: S-tile = mfma(A=K, B=Q) -> C: col=lane&15=token,
// row=quad*4+reg=key. Key-id bijection chosen so P re-enters PV's A-operand
// in-lane: PV pair P (32 keys): A[tok][kk=quad*8+j] = j<4 ? s[2P][j] : s[2P+1][j-4].
__global__ __launch_bounds__(256) void attn_mfma_kernel(
    const u16* __restrict__ q, const float* __restrict__ kg,
    const float* __restrict__ vg, u16* __restrict__ att)
{
    __shared__ u16 Kf[8192];   // A-frag order: [kt][lane][8]
    __shared__ u16 Vf[8192];   // B-frag order: [(P*2+dh)][lane][8]
    int tb = blockIdx.x & 255;
    int bh = blockIdx.x >> 8;
    int h = bh % NH, b = bh / NH;
    int tid = threadIdx.x;
    const float scale = 0.17677669529663687f;   // 1/sqrt(32)

    // ---- phase 0: stage K (pre-scaled) and V into fragment-ordered LDS ----
    for (int i = tid; i < 8192; i += 256) {
        int key = i >> 5, dim = i & 31;
        int gidx = (b * M_LEN + key) * C_DIM + h * HD + dim;
        {
            float f = kg[gidx] * scale;
            int kt = key >> 4, r = key & 15, qd = dim >> 3, j = dim & 7;
            Kf[kt * 512 + (qd * 16 + r) * 8 + j] = f2bf(f);
        }
        {
            float f = vg[gidx];
            int kt = key >> 4, r = key & 15;
            int qd = r >> 2, reg = r & 3;
            int P = kt >> 1;
            int j = reg + 4 * (kt & 1);
            int dh = dim >> 4, n = dim & 15;
            Vf[(P * 2 + dh) * 512 + (qd * 16 + n) * 8 + j] = f2bf(f);
        }
    }
    __syncthreads();

    int wave = tid >> 6, lane = tid & 63;
    int quad = lane >> 4, ln = lane & 15;
    int token0 = tb * 64 + wave * 16;

    // Q B-frag: B[k=dim][n=token]: token=ln, dims quad*8..+7 (16B aligned load)
    const u16* qrow = q + ((size_t)(b * N_TOK + token0 + ln)) * C_DIM + h * HD + quad * 8;
    short8v qf = *(const short8v*)qrow;

    // QK^T: 16 MFMAs
    float4v s[16];
#pragma unroll
    for (int kt = 0; kt < 16; ++kt) {
        short8v kf = *(const short8v*)&Kf[kt * 512 + lane * 8];
        float4v z = {0.f, 0.f, 0.f, 0.f};
        s[kt] = __builtin_amdgcn_mfma_f32_16x16x32_bf16(kf, qf, z, 0, 0, 0);
    }

    // softmax over 256 keys: 64 in-lane + butterflies over the 4 quads
    float mx = -1e30f;
#pragma unroll
    for (int kt = 0; kt < 16; ++kt) {
#pragma unroll
        for (int r = 0; r < 4; ++r) mx = fmaxf(mx, s[kt][r]);
    }
    mx = fmaxf(mx, __shfl_xor(mx, 16));
    mx = fmaxf(mx, __shfl_xor(mx, 32));
    float l = 0.f;
#pragma unroll
    for (int kt = 0; kt < 16; ++kt) {
#pragma unroll
        for (int r = 0; r < 4; ++r) {
            float p = __expf(s[kt][r] - mx);
            s[kt][r] = p;
            l += p;
        }
    }
    l += __shfl_xor(l, 16);
    l += __shfl_xor(l, 32);
    float inv = 1.f / l;

    // PV: 8 pairs x 2 dim-halves, P packed in-lane (no shuffles, no LDS trip)
    float4v o0 = {0.f, 0.f, 0.f, 0.f}, o1 = {0.f, 0.f, 0.f, 0.f};
#pragma unroll
    for (int P = 0; P < 8; ++P) {
        short8v pf;
#pragma unroll
        for (int j = 0; j < 4; ++j) {
            pf[j]     = (short)f2bf(s[2 * P][j]);
            pf[j + 4] = (short)f2bf(s[2 * P + 1][j]);
        }
        short8v v0 = *(const short8v*)&Vf[(P * 2 + 0) * 512 + lane * 8];
        short8v v1 = *(const short8v*)&Vf[(P * 2 + 1) * 512 + lane * 8];
        o0 = __builtin_amdgcn_mfma_f32_16x16x32_bf16(pf, v0, o0, 0, 0, 0);
        o1 = __builtin_amdgcn_mfma_f32_16x16x32_bf16(pf, v1, o1, 0, 0, 0);
    }

    // normalize + store: O row=token=quad*4+reg, col=dim=ln (+16 for o1)
#pragma unroll
    for (int r = 0; r < 4; ++r) {
        float invr = __shfl(inv, quad * 4 + r);
        u16* row = att + ((size_t)(b * N_TOK + token0 + quad * 4 + r)) * C_DIM + h * HD;
        row[ln]      = f2bf(o0[r] * invr);
        row[16 + ln] = f2bf(o1[r] * invr);
    }
}

// ---------------- Kernel D: out projection + bias + residual (y fp32) ------
__global__ __launch_bounds__(192) void proj_res_kernel(
    const u16* __restrict__ att, const float* __restrict__ Wp,
    const float* __restrict__ bp, const float* __restrict__ x,
    float* __restrict__ y)
{
    __shared__ float fs[C_DIM * (TILE_N + 1)];   // [j][nn], stride 17
    int b = blockIdx.x >> 10;
    int n0 = (blockIdx.x & 1023) * TILE_N;
    int tid = threadIdx.x;   // j = tid
#pragma unroll
    for (int nn = 0; nn < TILE_N; ++nn) {
        fs[tid * (TILE_N + 1) + nn] =
            bf2f(att[(size_t)(b * N_TOK + n0 + nn) * C_DIM + tid]);
    }
    __syncthreads();
    int c = tid;
    float acc[TILE_N];
#pragma unroll
    for (int nn = 0; nn < TILE_N; ++nn) acc[nn] = 0.f;
    for (int j = 0; j < C_DIM; ++j) {
        float w = Wp[j * C_DIM + c];
        const float* row = &fs[j * (TILE_N + 1)];
#pragma unroll
        for (int nn = 0; nn < TILE_N; ++nn) acc[nn] += row[nn] * w;
    }
    float bias = bp[c];
    size_t base = ((size_t)(b * C_DIM + c) << 14) + n0;
    const float4* xv = (const float4*)(x + base);
    float4* yv = (float4*)(y + base);
#pragma unroll
    for (int i4 = 0; i4 < 4; ++i4) {
        float4 u = xv[i4];
        float4 w;
        w.x = acc[4 * i4 + 0] + bias + u.x;
        w.y = acc[4 * i4 + 1] + bias + u.y;
        w.z = acc[4 * i4 + 2] + bias + u.z;
        w.w = acc[4 * i4 + 3] + bias + u.w;
        yv[i4] = w;
    }
}

extern "C" void kernel_launch(void* const* d_in, const int* in_sizes, int n_in,
                              void* d_out, int out_size, void* d_ws, size_t ws_size,
                              hipStream_t stream) {
    const float* x     = (const float*)d_in[0];
    const float* prior = (const float*)d_in[1];
    const float* ln1_g = (const float*)d_in[2];
    const float* ln1_b = (const float*)d_in[3];
    const float* ln2_g = (const float*)d_in[4];
    const float* ln2_b = (const float*)d_in[5];
    const float* Wq    = (const float*)d_in[6];
    const float* Wkv   = (const float*)d_in[7];
    const float* Wp    = (const float*)d_in[8];
    const float* bp    = (const float*)d_in[9];

    // d_out (50.3 MB fp32) multiplexed:
    //   [0, 25.2MB):     q bf16   (A -> C)
    //   [25.2, 26.0MB):  k fp32   (B -> C)
    //   [26.0, 26.7MB):  v fp32   (B -> C)
    //   proj_res finally overwrites all of d_out with y.
    // d_ws: att bf16 (25.2 MB).
    char* outc = (char*)d_out;
    u16*   q    = (u16*)outc;
    float* kbuf = (float*)(outc + 25165824);
    float* vbuf = (float*)(outc + 25165824 + 786432);
    u16*   att  = (u16*)d_ws;
    float* y    = (float*)d_out;

    ln1_q_kernel<<<4096, 192, 0, stream>>>(x, ln1_g, ln1_b, Wq, q);
    ln2_kv_kernel<<<1024, 192, 0, stream>>>(prior, ln2_g, ln2_b, Wkv, kbuf, vbuf);
    attn_mfma_kernel<<<6144, 256, 0, stream>>>(q, kbuf, vbuf, att);
    proj_res_kernel<<<4096, 192, 0, stream>>>(att, Wp, bp, x, y);
}

// Round 7
// 263.010 us; speedup vs baseline: 3.1814x; 1.5550x over previous
//
#include <hip/hip_runtime.h>

typedef unsigned short u16;
typedef unsigned int u32;

#define C_DIM 192
#define N_TOK 16384
#define M_LEN 256
#define HD 32
#define NH 6

#define AF_STRIDE 3080   // u16 per-token-tile A-frag region (6*512 + 8 skew)

typedef __attribute__((ext_vector_type(8))) short short8v;
typedef __attribute__((ext_vector_type(4))) float float4v;

__device__ __forceinline__ float bf2f(u32 u) {
    union { u32 i; float f; } v; v.i = (u & 0xffffu) << 16; return v.f;
}
__device__ __forceinline__ u16 f2bf(float f) {
    union { float f; u32 i; } v; v.f = f;
    u32 x = v.i;
    return (u16)((x + 0x7fffu + ((x >> 16) & 1u)) >> 16);
}

// ---------------- Kernel A: LN1 + Q projection via MFMA ----------------
// grid: 4*256 = 1024 blocks, 256 threads. Block: 64 tokens x 192 outputs.
// wave w computes output cols 48w..48w+47 for all 64 tokens.
__global__ __launch_bounds__(256) void ln1_q_mfma(
    const float* __restrict__ x, const float* __restrict__ g,
    const float* __restrict__ beta, const float* __restrict__ Wq,
    u16* __restrict__ q)
{
    __shared__ u16 Af[4 * AF_STRIDE];      // A-frags, 4 token-tiles
    __shared__ u16 Tq[64 * 200];           // [tok][c] transpose, stride 200
    __shared__ float part[64][4][2];
    __shared__ float mu_s[64], rs_s[64];
    int b = blockIdx.x >> 8;
    int n0 = (blockIdx.x & 255) * 64;
    int t = threadIdx.x;
    int wv = t >> 6, lane = t & 63;

    // ---- phase 1: load x slice into regs (wave w: c in [48w,48w+48)) ----
    float xv[48];
    {
        const float* xb = x + (((size_t)(b * C_DIM + wv * 48)) << 14) + n0 + lane;
        float s1 = 0.f, s2 = 0.f;
#pragma unroll
        for (int i = 0; i < 48; ++i) {
            float f = xb[(size_t)i << 14];
            xv[i] = f; s1 += f; s2 += f * f;
        }
        part[lane][wv][0] = s1; part[lane][wv][1] = s2;
    }
    __syncthreads();
    if (t < 64) {
        float a  = part[t][0][0] + part[t][1][0] + part[t][2][0] + part[t][3][0];
        float c2 = part[t][0][1] + part[t][1][1] + part[t][2][1] + part[t][3][1];
        float mu = a * (1.f / C_DIM);
        mu_s[t] = mu;
        rs_s[t] = rsqrtf(c2 * (1.f / C_DIM) - mu * mu + 1e-5f);
    }
    __syncthreads();

    // ---- phase 2: normalize, pack bf16 pairs into A-frag LDS ----
    {
        float mu = mu_s[lane], rs = rs_s[lane];
        int mt2 = lane >> 4, ln2 = lane & 15;   // token decomposition
        u32* A32 = (u32*)Af;
#pragma unroll
        for (int i = 0; i < 48; i += 2) {
            int c = wv * 48 + i;
            float f0 = (xv[i]     - mu) * rs * g[c]     + beta[c];
            float f1 = (xv[i + 1] - mu) * rs * g[c + 1] + beta[c + 1];
            int kt = c >> 5, k8 = (c & 31) >> 3, j = c & 7;
            u32 val = (u32)f2bf(f0) | ((u32)f2bf(f1) << 16);
            A32[(mt2 * AF_STRIDE + kt * 512 + k8 * 128 + ln2 * 8 + j) >> 1] = val;
        }
    }
    __syncthreads();

    // ---- phase 3: Wq B-frags (cols 48w..48w+47) into VGPRs ----
    int q8 = lane >> 4, ln = lane & 15;
    short8v Bf[18];
#pragma unroll
    for (int kt = 0; kt < 6; ++kt) {
#pragma unroll
        for (int jj = 0; jj < 3; ++jj) {
            const float* w0 = Wq + (kt * 32 + q8 * 8) * C_DIM + (wv * 3 + jj) * 16 + ln;
            short8v f;
#pragma unroll
            for (int j = 0; j < 8; ++j) f[j] = (short)f2bf(w0[j * C_DIM]);
            Bf[kt * 3 + jj] = f;
        }
    }

    // ---- phase 4: MFMA + write C to transpose LDS ----
#pragma unroll
    for (int mt = 0; mt < 4; ++mt) {
        float4v acc[3] = {{0.f,0.f,0.f,0.f},{0.f,0.f,0.f,0.f},{0.f,0.f,0.f,0.f}};
#pragma unroll
        for (int kt = 0; kt < 6; ++kt) {
            short8v a = *(const short8v*)&Af[mt * AF_STRIDE + kt * 512 + lane * 8];
#pragma unroll
            for (int jj = 0; jj < 3; ++jj)
                acc[jj] = __builtin_amdgcn_mfma_f32_16x16x32_bf16(a, Bf[kt * 3 + jj], acc[jj], 0, 0, 0);
        }
#pragma unroll
        for (int jj = 0; jj < 3; ++jj)
#pragma unroll
            for (int r = 0; r < 4; ++r)
                Tq[(mt * 16 + q8 * 4 + r) * 200 + (wv * 3 + jj) * 16 + ln] = f2bf(acc[jj][r]);
    }
    __syncthreads();

    // ---- phase 5: vectorized q store (48 u16 = 6 uint4 per chunk!) ----
    {
        int tok = t >> 2, pp = t & 3;
        const uint4* src = (const uint4*)&Tq[tok * 200 + pp * 48];
        uint4* dst = (uint4*)(q + ((size_t)(b * N_TOK + n0 + tok)) * C_DIM + pp * 48);
#pragma unroll
        for (int i = 0; i < 6; ++i) dst[i] = src[i];
    }
}

// ---------------- Kernel B: LN2 + KV projection (fp32 k/v -> d_out hi) -----
__global__ __launch_bounds__(192) void ln2_kv_kernel(
    const float* __restrict__ prior, const float* __restrict__ g,
    const float* __restrict__ beta, const float* __restrict__ Wkv,
    float* __restrict__ k, float* __restrict__ v)
{
    __shared__ float pr[C_DIM];
    __shared__ float stats[2];
    int row = blockIdx.x;
    int tid = threadIdx.x;
    float val = prior[row * C_DIM + tid];
    pr[tid] = val;
    __syncthreads();
    if (tid == 0) {
        float s = 0.f, s2 = 0.f;
        for (int c = 0; c < C_DIM; ++c) { float t = pr[c]; s += t; s2 += t * t; }
        float mu = s * (1.f / C_DIM);
        stats[0] = mu;
        stats[1] = rsqrtf(s2 * (1.f / C_DIM) - mu * mu + 1e-5f);
    }
    __syncthreads();
    float xn = (val - stats[0]) * stats[1] * g[tid] + beta[tid];
    __syncthreads();
    pr[tid] = xn;
    __syncthreads();
    float ka = 0.f, va = 0.f;
    for (int c = 0; c < C_DIM; ++c) {
        float p = pr[c];
        ka += p * Wkv[c * 384 + tid];
        va += p * Wkv[c * 384 + 192 + tid];
    }
    k[row * C_DIM + tid] = ka;
    v[row * C_DIM + tid] = va;
}

// ---------------- Kernel C: MFMA attention (unchanged, verified) -----------
__global__ __launch_bounds__(256) void attn_mfma_kernel(
    const u16* __restrict__ q, const float* __restrict__ kg,
    const float* __restrict__ vg, u16* __restrict__ att)
{
    __shared__ u16 Kf[8192];
    __shared__ u16 Vf[8192];
    int tb = blockIdx.x & 255;
    int bh = blockIdx.x >> 8;
    int h = bh % NH, b = bh / NH;
    int tid = threadIdx.x;
    const float scale = 0.17677669529663687f;

    for (int i = tid; i < 8192; i += 256) {
        int key = i >> 5, dim = i & 31;
        int gidx = (b * M_LEN + key) * C_DIM + h * HD + dim;
        {
            float f = kg[gidx] * scale;
            int kt = key >> 4, r = key & 15, qd = dim >> 3, j = dim & 7;
            Kf[kt * 512 + (qd * 16 + r) * 8 + j] = f2bf(f);
        }
        {
            float f = vg[gidx];
            int kt = key >> 4, r = key & 15;
            int qd = r >> 2, reg = r & 3;
            int P = kt >> 1;
            int j = reg + 4 * (kt & 1);
            int dh = dim >> 4, n = dim & 15;
            Vf[(P * 2 + dh) * 512 + (qd * 16 + n) * 8 + j] = f2bf(f);
        }
    }
    __syncthreads();

    int wave = tid >> 6, lane = tid & 63;
    int quad = lane >> 4, ln = lane & 15;
    int token0 = tb * 64 + wave * 16;

    const u16* qrow = q + ((size_t)(b * N_TOK + token0 + ln)) * C_DIM + h * HD + quad * 8;
    short8v qf = *(const short8v*)qrow;

    float4v s[16];
#pragma unroll
    for (int kt = 0; kt < 16; ++kt) {
        short8v kf = *(const short8v*)&Kf[kt * 512 + lane * 8];
        float4v z = {0.f, 0.f, 0.f, 0.f};
        s[kt] = __builtin_amdgcn_mfma_f32_16x16x32_bf16(kf, qf, z, 0, 0, 0);
    }

    float mx = -1e30f;
#pragma unroll
    for (int kt = 0; kt < 16; ++kt) {
#pragma unroll
        for (int r = 0; r < 4; ++r) mx = fmaxf(mx, s[kt][r]);
    }
    mx = fmaxf(mx, __shfl_xor(mx, 16));
    mx = fmaxf(mx, __shfl_xor(mx, 32));
    float l = 0.f;
#pragma unroll
    for (int kt = 0; kt < 16; ++kt) {
#pragma unroll
        for (int r = 0; r < 4; ++r) {
            float p = __expf(s[kt][r] - mx);
            s[kt][r] = p;
            l += p;
        }
    }
    l += __shfl_xor(l, 16);
    l += __shfl_xor(l, 32);
    float inv = 1.f / l;

    float4v o0 = {0.f, 0.f, 0.f, 0.f}, o1 = {0.f, 0.f, 0.f, 0.f};
#pragma unroll
    for (int P = 0; P < 8; ++P) {
        short8v pf;
#pragma unroll
        for (int j = 0; j < 4; ++j) {
            pf[j]     = (short)f2bf(s[2 * P][j]);
            pf[j + 4] = (short)f2bf(s[2 * P + 1][j]);
        }
        short8v v0 = *(const short8v*)&Vf[(P * 2 + 0) * 512 + lane * 8];
        short8v v1 = *(const short8v*)&Vf[(P * 2 + 1) * 512 + lane * 8];
        o0 = __builtin_amdgcn_mfma_f32_16x16x32_bf16(pf, v0, o0, 0, 0, 0);
        o1 = __builtin_amdgcn_mfma_f32_16x16x32_bf16(pf, v1, o1, 0, 0, 0);
    }

#pragma unroll
    for (int r = 0; r < 4; ++r) {
        float invr = __shfl(inv, quad * 4 + r);
        u16* row = att + ((size_t)(b * N_TOK + token0 + quad * 4 + r)) * C_DIM + h * HD;
        row[ln]      = f2bf(o0[r] * invr);
        row[16 + ln] = f2bf(o1[r] * invr);
    }
}

// ---------------- Kernel D: out projection + residual via MFMA --------------
// grid: 1024 blocks, 256 threads. Block: 64 tokens x 192 cols.
__global__ __launch_bounds__(256) void proj_res_mfma(
    const u16* __restrict__ att, const float* __restrict__ Wp,
    const float* __restrict__ bp, const float* __restrict__ x,
    float* __restrict__ y)
{
    __shared__ float Tf[C_DIM * 68];   // [c][tok] fp32 transpose, stride 68
    int b = blockIdx.x >> 8;
    int n0 = (blockIdx.x & 255) * 64;
    int t = threadIdx.x;
    int wv = t >> 6, lane = t & 63;
    int q8 = lane >> 4, ln = lane & 15;

    // Wp B-frags: wave w covers cols 48w..48w+47
    short8v Bf[18];
#pragma unroll
    for (int kt = 0; kt < 6; ++kt) {
#pragma unroll
        for (int jj = 0; jj < 3; ++jj) {
            const float* w0 = Wp + (kt * 32 + q8 * 8) * C_DIM + (wv * 3 + jj) * 16 + ln;
            short8v f;
#pragma unroll
            for (int j = 0; j < 8; ++j) f[j] = (short)f2bf(w0[j * C_DIM]);
            Bf[kt * 3 + jj] = f;
        }
    }

#pragma unroll
    for (int mt = 0; mt < 4; ++mt) {
        const u16* ab = att + ((size_t)(b * N_TOK + n0 + mt * 16 + ln)) * C_DIM + q8 * 8;
        float4v acc[3] = {{0.f,0.f,0.f,0.f},{0.f,0.f,0.f,0.f},{0.f,0.f,0.f,0.f}};
#pragma unroll
        for (int kt = 0; kt < 6; ++kt) {
            short8v a = *(const short8v*)(ab + kt * 32);
#pragma unroll
            for (int jj = 0; jj < 3; ++jj)
                acc[jj] = __builtin_amdgcn_mfma_f32_16x16x32_bf16(a, Bf[kt * 3 + jj], acc[jj], 0, 0, 0);
        }
#pragma unroll
        for (int jj = 0; jj < 3; ++jj)
#pragma unroll
            for (int r = 0; r < 4; ++r)
                Tf[((wv * 3 + jj) * 16 + ln) * 68 + mt * 16 + q8 * 4 + r] = acc[jj][r];
    }
    __syncthreads();

    // epilogue: thread c handles one channel row (64 tokens)
    if (t < C_DIM) {
        int c = t;
        float bias = bp[c];
        const float4* xr = (const float4*)(x + (((size_t)(b * C_DIM + c)) << 14) + n0);
        float4*       yr = (float4*)(y + (((size_t)(b * C_DIM + c)) << 14) + n0);
        const float4* tr = (const float4*)&Tf[c * 68];
#pragma unroll
        for (int i = 0; i < 16; ++i) {
            float4 u = xr[i], a = tr[i];
            float4 w;
            w.x = a.x + bias + u.x;
            w.y = a.y + bias + u.y;
            w.z = a.z + bias + u.z;
            w.w = a.w + bias + u.w;
            yr[i] = w;
        }
    }
}

extern "C" void kernel_launch(void* const* d_in, const int* in_sizes, int n_in,
                              void* d_out, int out_size, void* d_ws, size_t ws_size,
                              hipStream_t stream) {
    const float* x     = (const float*)d_in[0];
    const float* prior = (const float*)d_in[1];
    const float* ln1_g = (const float*)d_in[2];
    const float* ln1_b = (const float*)d_in[3];
    const float* ln2_g = (const float*)d_in[4];
    const float* ln2_b = (const float*)d_in[5];
    const float* Wq    = (const float*)d_in[6];
    const float* Wkv   = (const float*)d_in[7];
    const float* Wp    = (const float*)d_in[8];
    const float* bp    = (const float*)d_in[9];

    // d_out (50.3 MB fp32) multiplexed:
    //   [0, 25.2MB):     q bf16   (A -> C)
    //   [25.2, 26.0MB):  k fp32   (B -> C)
    //   [26.0, 26.7MB):  v fp32   (B -> C)
    //   proj_res finally overwrites all of d_out with y.
    // d_ws: att bf16 (25.2 MB) only.
    char* outc = (char*)d_out;
    u16*   q    = (u16*)outc;
    float* kbuf = (float*)(outc + 25165824);
    float* vbuf = (float*)(outc + 25165824 + 786432);
    u16*   att  = (u16*)d_ws;
    float* y    = (float*)d_out;

    ln1_q_mfma<<<1024, 256, 0, stream>>>(x, ln1_g, ln1_b, Wq, q);
    ln2_kv_kernel<<<1024, 192, 0, stream>>>(prior, ln2_g, ln2_b, Wkv, kbuf, vbuf);
    attn_mfma_kernel<<<6144, 256, 0, stream>>>(q, kbuf, vbuf, att);
    proj_res_mfma<<<1024, 256, 0, stream>>>(att, Wp, bp, x, y);
}

// Round 8
// 243.081 us; speedup vs baseline: 3.4422x; 1.0820x over previous
//
#include <hip/hip_runtime.h>

typedef unsigned short u16;
typedef unsigned int u32;

#define C_DIM 192
#define N_TOK 16384
#define M_LEN 256
#define HD 32
#define NH 6

#define AF_STRIDE 3080   // u16 per-token-tile A-frag region (6*512 + 8 skew)

typedef __attribute__((ext_vector_type(8))) short short8v;
typedef __attribute__((ext_vector_type(4))) float float4v;

__device__ __forceinline__ float bf2f(u32 u) {
    union { u32 i; float f; } v; v.i = (u & 0xffffu) << 16; return v.f;
}
__device__ __forceinline__ u16 f2bf(float f) {
    union { float f; u32 i; } v; v.f = f;
    u32 x = v.i;
    return (u16)((x + 0x7fffu + ((x >> 16) & 1u)) >> 16);
}

// ---------------- Kernel W: Wq -> fragment-ordered bf16 ----------------
// 72 frags (wv 0..3, kt 0..5, jj 0..2), each 64 lanes x 8 u16.
// grid: 18 blocks x 256 threads.
__global__ __launch_bounds__(256) void wq_prep(
    const float* __restrict__ Wq, u16* __restrict__ WqF)
{
    int gt = blockIdx.x * 256 + threadIdx.x;
    int f = gt >> 6, lane = gt & 63;
    int q8 = lane >> 4, ln = lane & 15;
    int wv = f / 18, r = f % 18;
    int kt = r / 3, jj = r % 3;
    const float* w0 = Wq + (kt * 32 + q8 * 8) * C_DIM + (wv * 3 + jj) * 16 + ln;
    short8v out;
#pragma unroll
    for (int j = 0; j < 8; ++j) out[j] = (short)f2bf(w0[j * C_DIM]);
    *(short8v*)&WqF[f * 512 + lane * 8] = out;
}

// ---------------- Kernel A: LN1 + Q projection via MFMA ----------------
// grid: 1024 blocks, 256 threads. Block: 64 tokens x 192 outputs.
__global__ __launch_bounds__(256) void ln1_q_mfma(
    const float* __restrict__ x, const float* __restrict__ g,
    const float* __restrict__ beta, const u16* __restrict__ WqF,
    u16* __restrict__ q)
{
    __shared__ u16 Af[4 * AF_STRIDE];      // A-frags, 4 token-tiles
    __shared__ u16 Tq[64 * 200];           // [tok][c] transpose, stride 200
    __shared__ float part[64][4][2];
    __shared__ float mu_s[64], rs_s[64];
    int b = blockIdx.x >> 8;
    int n0 = (blockIdx.x & 255) * 64;
    int t = threadIdx.x;
    int wv = t >> 6, lane = t & 63;

    // ---- phase 1: load x slice into regs (wave w: c in [48w,48w+48)) ----
    float xv[48];
    {
        const float* xb = x + (((size_t)(b * C_DIM + wv * 48)) << 14) + n0 + lane;
        float s1 = 0.f, s2 = 0.f;
#pragma unroll
        for (int i = 0; i < 48; ++i) {
            float f = xb[(size_t)i << 14];
            xv[i] = f; s1 += f; s2 += f * f;
        }
        part[lane][wv][0] = s1; part[lane][wv][1] = s2;
    }
    __syncthreads();
    if (t < 64) {
        float a  = part[t][0][0] + part[t][1][0] + part[t][2][0] + part[t][3][0];
        float c2 = part[t][0][1] + part[t][1][1] + part[t][2][1] + part[t][3][1];
        float mu = a * (1.f / C_DIM);
        mu_s[t] = mu;
        rs_s[t] = rsqrtf(c2 * (1.f / C_DIM) - mu * mu + 1e-5f);
    }
    __syncthreads();

    // ---- phase 2: normalize, pack bf16 pairs into A-frag LDS ----
    {
        float mu = mu_s[lane], rs = rs_s[lane];
        int mt2 = lane >> 4, ln2 = lane & 15;
        u32* A32 = (u32*)Af;
#pragma unroll
        for (int i = 0; i < 48; i += 2) {
            int c = wv * 48 + i;
            float f0 = (xv[i]     - mu) * rs * g[c]     + beta[c];
            float f1 = (xv[i + 1] - mu) * rs * g[c + 1] + beta[c + 1];
            int kt = c >> 5, k8 = (c & 31) >> 3, j = c & 7;
            u32 val = (u32)f2bf(f0) | ((u32)f2bf(f1) << 16);
            A32[(mt2 * AF_STRIDE + kt * 512 + k8 * 128 + ln2 * 8 + j) >> 1] = val;
        }
    }
    __syncthreads();

    // ---- phase 3: Wq B-frags from prepped buffer (coalesced 16B loads) ----
    int q8 = lane >> 4, ln = lane & 15;
    short8v Bf[18];
#pragma unroll
    for (int i = 0; i < 18; ++i)
        Bf[i] = *(const short8v*)&WqF[(wv * 18 + i) * 512 + lane * 8];

    // ---- phase 4: MFMA + write C to transpose LDS ----
#pragma unroll
    for (int mt = 0; mt < 4; ++mt) {
        float4v acc[3] = {{0.f,0.f,0.f,0.f},{0.f,0.f,0.f,0.f},{0.f,0.f,0.f,0.f}};
#pragma unroll
        for (int kt = 0; kt < 6; ++kt) {
            short8v a = *(const short8v*)&Af[mt * AF_STRIDE + kt * 512 + lane * 8];
#pragma unroll
            for (int jj = 0; jj < 3; ++jj)
                acc[jj] = __builtin_amdgcn_mfma_f32_16x16x32_bf16(a, Bf[kt * 3 + jj], acc[jj], 0, 0, 0);
        }
#pragma unroll
        for (int jj = 0; jj < 3; ++jj)
#pragma unroll
            for (int r = 0; r < 4; ++r)
                Tq[(mt * 16 + q8 * 4 + r) * 200 + (wv * 3 + jj) * 16 + ln] = f2bf(acc[jj][r]);
    }
    __syncthreads();

    // ---- phase 5: vectorized q store (48 u16 = 6 uint4 per chunk) ----
    {
        int tok = t >> 2, pp = t & 3;
        const uint4* src = (const uint4*)&Tq[tok * 200 + pp * 48];
        uint4* dst = (uint4*)(q + ((size_t)(b * N_TOK + n0 + tok)) * C_DIM + pp * 48);
#pragma unroll
        for (int i = 0; i < 6; ++i) dst[i] = src[i];
    }
}

// ---------------- Kernel B: LN2 + KV projection (fp32 k/v) ----------------
__global__ __launch_bounds__(192) void ln2_kv_kernel(
    const float* __restrict__ prior, const float* __restrict__ g,
    const float* __restrict__ beta, const float* __restrict__ Wkv,
    float* __restrict__ k, float* __restrict__ v)
{
    __shared__ float pr[C_DIM];
    __shared__ float stats[2];
    int row = blockIdx.x;
    int tid = threadIdx.x;
    float val = prior[row * C_DIM + tid];
    pr[tid] = val;
    __syncthreads();
    if (tid == 0) {
        float s = 0.f, s2 = 0.f;
        for (int c = 0; c < C_DIM; ++c) { float t = pr[c]; s += t; s2 += t * t; }
        float mu = s * (1.f / C_DIM);
        stats[0] = mu;
        stats[1] = rsqrtf(s2 * (1.f / C_DIM) - mu * mu + 1e-5f);
    }
    __syncthreads();
    float xn = (val - stats[0]) * stats[1] * g[tid] + beta[tid];
    __syncthreads();
    pr[tid] = xn;
    __syncthreads();
    float ka = 0.f, va = 0.f;
    for (int c = 0; c < C_DIM; ++c) {
        float p = pr[c];
        ka += p * Wkv[c * 384 + tid];
        va += p * Wkv[c * 384 + 192 + tid];
    }
    k[row * C_DIM + tid] = ka;
    v[row * C_DIM + tid] = va;
}

// ---------------- Kernel KV: pack K/V into fragment-ordered bf16 ----------
// grid: 24 blocks (b*NH+h), 256 threads. Runs ONCE per (b,h) tile.
__global__ __launch_bounds__(256) void kv_prep(
    const float* __restrict__ kg, const float* __restrict__ vg,
    u16* __restrict__ KfG, u16* __restrict__ VfG)
{
    int bh = blockIdx.x;
    int h = bh % NH, b = bh / NH;
    int tid = threadIdx.x;
    const float scale = 0.17677669529663687f;
    u16* Kd = KfG + bh * 8192;
    u16* Vd = VfG + bh * 8192;
    for (int i = tid; i < 8192; i += 256) {
        int key = i >> 5, dim = i & 31;
        int gidx = (b * M_LEN + key) * C_DIM + h * HD + dim;
        {
            float f = kg[gidx] * scale;
            int kt = key >> 4, r = key & 15, qd = dim >> 3, j = dim & 7;
            Kd[kt * 512 + (qd * 16 + r) * 8 + j] = f2bf(f);
        }
        {
            float f = vg[gidx];
            int kt = key >> 4, r = key & 15;
            int qd = r >> 2, reg = r & 3;
            int P = kt >> 1;
            int j = reg + 4 * (kt & 1);
            int dh = dim >> 4, n = dim & 15;
            Vd[(P * 2 + dh) * 512 + (qd * 16 + n) * 8 + j] = f2bf(f);
        }
    }
}

// ---------------- Kernel C: MFMA attention v3 ----------------
// grid: B*NH*64 = 1536 blocks, 256 threads. Block: 256 tokens (4 reps/wave).
// Staging = pure uint4 copy of prepped fragments (conflict-free).
__global__ __launch_bounds__(256) void attn_mfma_kernel(
    const u16* __restrict__ q, const u16* __restrict__ KfG,
    const u16* __restrict__ VfG, u16* __restrict__ att)
{
    __shared__ u16 sh[16384];   // [0,8192): Kf, [8192,16384): Vf
    int tb = blockIdx.x & 63;
    int bh = blockIdx.x >> 6;
    int h = bh % NH, b = bh / NH;
    int tid = threadIdx.x;

    {
        const uint4* Ks = (const uint4*)(KfG + bh * 8192);
        const uint4* Vs = (const uint4*)(VfG + bh * 8192);
        uint4* d = (uint4*)sh;
#pragma unroll
        for (int i = tid; i < 2048; i += 256)
            d[i] = (i < 1024) ? Ks[i] : Vs[i - 1024];
    }
    __syncthreads();

    const u16* Kf = sh;
    const u16* Vf = sh + 8192;
    int wave = tid >> 6, lane = tid & 63;
    int quad = lane >> 4, ln = lane & 15;

    for (int rep = 0; rep < 4; ++rep) {
        int token0 = tb * 256 + rep * 64 + wave * 16;

        const u16* qrow = q + ((size_t)(b * N_TOK + token0 + ln)) * C_DIM + h * HD + quad * 8;
        short8v qf = *(const short8v*)qrow;

        float4v s[16];
#pragma unroll
        for (int kt = 0; kt < 16; ++kt) {
            short8v kf = *(const short8v*)&Kf[kt * 512 + lane * 8];
            float4v z = {0.f, 0.f, 0.f, 0.f};
            s[kt] = __builtin_amdgcn_mfma_f32_16x16x32_bf16(kf, qf, z, 0, 0, 0);
        }

        float mx = -1e30f;
#pragma unroll
        for (int kt = 0; kt < 16; ++kt) {
#pragma unroll
            for (int r = 0; r < 4; ++r) mx = fmaxf(mx, s[kt][r]);
        }
        mx = fmaxf(mx, __shfl_xor(mx, 16));
        mx = fmaxf(mx, __shfl_xor(mx, 32));
        float l = 0.f;
#pragma unroll
        for (int kt = 0; kt < 16; ++kt) {
#pragma unroll
            for (int r = 0; r < 4; ++r) {
                float p = __expf(s[kt][r] - mx);
                s[kt][r] = p;
                l += p;
            }
        }
        l += __shfl_xor(l, 16);
        l += __shfl_xor(l, 32);
        float inv = 1.f / l;

        float4v o0 = {0.f, 0.f, 0.f, 0.f}, o1 = {0.f, 0.f, 0.f, 0.f};
#pragma unroll
        for (int P = 0; P < 8; ++P) {
            short8v pf;
#pragma unroll
            for (int j = 0; j < 4; ++j) {
                pf[j]     = (short)f2bf(s[2 * P][j]);
                pf[j + 4] = (short)f2bf(s[2 * P + 1][j]);
            }
            short8v v0 = *(const short8v*)&Vf[(P * 2 + 0) * 512 + lane * 8];
            short8v v1 = *(const short8v*)&Vf[(P * 2 + 1) * 512 + lane * 8];
            o0 = __builtin_amdgcn_mfma_f32_16x16x32_bf16(pf, v0, o0, 0, 0, 0);
            o1 = __builtin_amdgcn_mfma_f32_16x16x32_bf16(pf, v1, o1, 0, 0, 0);
        }

#pragma unroll
        for (int r = 0; r < 4; ++r) {
            float invr = __shfl(inv, quad * 4 + r);
            u16* row = att + ((size_t)(b * N_TOK + token0 + quad * 4 + r)) * C_DIM + h * HD;
            row[ln]      = f2bf(o0[r] * invr);
            row[16 + ln] = f2bf(o1[r] * invr);
        }
    }
}

// ---------------- Kernel D: out projection + residual via MFMA --------------
__global__ __launch_bounds__(256) void proj_res_mfma(
    const u16* __restrict__ att, const float* __restrict__ Wp,
    const float* __restrict__ bp, const float* __restrict__ x,
    float* __restrict__ y)
{
    __shared__ float Tf[C_DIM * 68];   // [c][tok] fp32 transpose, stride 68
    int b = blockIdx.x >> 8;
    int n0 = (blockIdx.x & 255) * 64;
    int t = threadIdx.x;
    int wv = t >> 6, lane = t & 63;
    int q8 = lane >> 4, ln = lane & 15;

    short8v Bf[18];
#pragma unroll
    for (int kt = 0; kt < 6; ++kt) {
#pragma unroll
        for (int jj = 0; jj < 3; ++jj) {
            const float* w0 = Wp + (kt * 32 + q8 * 8) * C_DIM + (wv * 3 + jj) * 16 + ln;
            short8v f;
#pragma unroll
            for (int j = 0; j < 8; ++j) f[j] = (short)f2bf(w0[j * C_DIM]);
            Bf[kt * 3 + jj] = f;
        }
    }

#pragma unroll
    for (int mt = 0; mt < 4; ++mt) {
        const u16* ab = att + ((size_t)(b * N_TOK + n0 + mt * 16 + ln)) * C_DIM + q8 * 8;
        float4v acc[3] = {{0.f,0.f,0.f,0.f},{0.f,0.f,0.f,0.f},{0.f,0.f,0.f,0.f}};
#pragma unroll
        for (int kt = 0; kt < 6; ++kt) {
            short8v a = *(const short8v*)(ab + kt * 32);
#pragma unroll
            for (int jj = 0; jj < 3; ++jj)
                acc[jj] = __builtin_amdgcn_mfma_f32_16x16x32_bf16(a, Bf[kt * 3 + jj], acc[jj], 0, 0, 0);
        }
#pragma unroll
        for (int jj = 0; jj < 3; ++jj)
#pragma unroll
            for (int r = 0; r < 4; ++r)
                Tf[((wv * 3 + jj) * 16 + ln) * 68 + mt * 16 + q8 * 4 + r] = acc[jj][r];
    }
    __syncthreads();

    if (t < C_DIM) {
        int c = t;
        float bias = bp[c];
        const float4* xr = (const float4*)(x + (((size_t)(b * C_DIM + c)) << 14) + n0);
        float4*       yr = (float4*)(y + (((size_t)(b * C_DIM + c)) << 14) + n0);
        const float4* tr = (const float4*)&Tf[c * 68];
#pragma unroll
        for (int i = 0; i < 16; ++i) {
            float4 u = xr[i], a = tr[i];
            float4 w;
            w.x = a.x + bias + u.x;
            w.y = a.y + bias + u.y;
            w.z = a.z + bias + u.z;
            w.w = a.w + bias + u.w;
            yr[i] = w;
        }
    }
}

extern "C" void kernel_launch(void* const* d_in, const int* in_sizes, int n_in,
                              void* d_out, int out_size, void* d_ws, size_t ws_size,
                              hipStream_t stream) {
    const float* x     = (const float*)d_in[0];
    const float* prior = (const float*)d_in[1];
    const float* ln1_g = (const float*)d_in[2];
    const float* ln1_b = (const float*)d_in[3];
    const float* ln2_g = (const float*)d_in[4];
    const float* ln2_b = (const float*)d_in[5];
    const float* Wq    = (const float*)d_in[6];
    const float* Wkv   = (const float*)d_in[7];
    const float* Wp    = (const float*)d_in[8];
    const float* bp    = (const float*)d_in[9];

    // d_out (50.3 MB fp32) multiplexed (y overwrites everything at the end):
    //   [0,        25165824): q bf16
    //   [25165824, 25952256): k fp32
    //   [25952256, 26738688): v fp32
    //   [26738688, 26812416): WqF  bf16 fragment-ordered (72 frags x 1KB)
    //   [26812416, 27205632): KfG  bf16 fragments (24 x 16KB)
    //   [27205632, 27598848): VfG  bf16 fragments (24 x 16KB)
    // d_ws: att bf16 (25.2 MB) only.
    char* outc = (char*)d_out;
    u16*   q    = (u16*)outc;
    float* kbuf = (float*)(outc + 25165824);
    float* vbuf = (float*)(outc + 25952256);
    u16*   WqF  = (u16*)(outc + 26738688);
    u16*   KfG  = (u16*)(outc + 26812416);
    u16*   VfG  = (u16*)(outc + 27205632);
    u16*   att  = (u16*)d_ws;
    float* y    = (float*)d_out;

    wq_prep<<<18, 256, 0, stream>>>(Wq, WqF);
    ln1_q_mfma<<<1024, 256, 0, stream>>>(x, ln1_g, ln1_b, WqF, q);
    ln2_kv_kernel<<<1024, 192, 0, stream>>>(prior, ln2_g, ln2_b, Wkv, kbuf, vbuf);
    kv_prep<<<24, 256, 0, stream>>>(kbuf, vbuf, KfG, VfG);
    attn_mfma_kernel<<<1536, 256, 0, stream>>>(q, KfG, VfG, att);
    proj_res_mfma<<<1024, 256, 0, stream>>>(att, Wp, bp, x, y);
}